// Round 1
// baseline (1021.578 us; speedup 1.0000x reference)
//
#include <hip/hip_runtime.h>
#include <math.h>
#include <float.h>

// Problem dims (fixed by setup_inputs)
#define BB 32
#define TT 2048
#define OO 128
#define CC 80
#define EPSF 1e-7f
#define NT 256

// ---------------------------------------------------------------------------
// Kernel 1: per-(b,t) log-softmax normalizers: xmax and lse = log(sum(exp(x-xmax)))
// ---------------------------------------------------------------------------
__global__ __launch_bounds__(NT) void lse_kernel(const float* __restrict__ cls,
                                                 float* __restrict__ xmax,
                                                 float* __restrict__ lse) {
#pragma clang fp contract(off)
    int bt = blockIdx.x * NT + threadIdx.x;
    if (bt >= BB * TT) return;
    const float* x = cls + (size_t)bt * CC;
    float m = x[0];
    for (int c = 1; c < CC; ++c) m = fmaxf(m, x[c]);
    float s = 0.f;
    for (int c = 0; c < CC; ++c) s += expf(x[c] - m);
    xmax[bt] = m;
    lse[bt] = logf(s);
}

// ---------------------------------------------------------------------------
// Kernel 2: cost[b][o][t] = giou_loss(pred[b,t], tgt[b,o]) + cls_nll(b,t,o)
// (stored transposed: rows = targets o, cols = tokens t — LSA row layout)
// fp32 op order mirrors the JAX reference exactly; contraction disabled.
// ---------------------------------------------------------------------------
__global__ __launch_bounds__(NT) void cost_kernel(const float* __restrict__ pb,
                                                  const float* __restrict__ tb,
                                                  const float* __restrict__ cls,
                                                  const int* __restrict__ tcls,
                                                  const float* __restrict__ xmax,
                                                  const float* __restrict__ lse,
                                                  float* __restrict__ cost) {
#pragma clang fp contract(off)
    int bo = blockIdx.x;
    int b = bo / OO;
    // target box (broadcast over t)
    float4 tbox = ((const float4*)tb)[bo];
    int tc = tcls[bo];
    float b2x1 = tbox.x - tbox.z / 2.f;
    float b2y1 = tbox.y - tbox.w / 2.f;
    float b2x2 = tbox.x + tbox.z / 2.f;
    float b2y2 = tbox.y + tbox.w / 2.f;
    float w2 = b2x2 - b2x1;
    float h2 = (b2y2 - b2y1) + EPSF;
    float w2h2 = w2 * h2;

    float* crow = cost + (size_t)bo * TT;

    for (int t = threadIdx.x; t < TT; t += NT) {
        size_t bt = (size_t)b * TT + t;
        float4 pbox = ((const float4*)pb)[bt];
        float b1x1 = pbox.x - pbox.z / 2.f;
        float b1y1 = pbox.y - pbox.w / 2.f;
        float b1x2 = pbox.x + pbox.z / 2.f;
        float b1y2 = pbox.y + pbox.w / 2.f;
        float w1 = b1x2 - b1x1;
        float h1 = (b1y2 - b1y1) + EPSF;

        float iw = fminf(b1x2, b2x2) - fmaxf(b1x1, b2x1);
        float ih = fminf(b1y2, b2y2) - fmaxf(b1y1, b2y1);
        iw = fmaxf(iw, 0.f);
        ih = fmaxf(ih, 0.f);
        float inter = iw * ih;
        float uni = ((w1 * h1 + w2h2) - inter) + EPSF;
        float iou = inter / uni;
        float cw = fmaxf(b1x2, b2x2) - fminf(b1x1, b2x1);
        float ch = fmaxf(b1y2, b2y2) - fminf(b1y1, b2y1);
        float c_area = (cw * ch) + EPSF;
        float giou = iou - (c_area - uni) / c_area;
        float bbox_loss = 1.0f - giou;

        // class NLL: -(shifted[tc] - lse)
        float xm = xmax[bt];
        float ls = lse[bt];
        float xc = cls[bt * CC + tc];
        float shifted = xc - xm;
        float cls_neg = -(shifted - ls);

        crow[t] = bbox_loss + cls_neg;
    }
}

// ---------------------------------------------------------------------------
// Kernel 3: Jonker-Volgenant shortest-augmenting-path LSA, one block per batch.
// All math in double, same expression order as the numpy reference; parallel
// masked argmin with first-index tie-breaking (matches np.argmin).
// ---------------------------------------------------------------------------
__global__ __launch_bounds__(NT) void lsa_kernel(const float* __restrict__ cost,
                                                 int* __restrict__ out) {
    int b = blockIdx.x;
    int tid = threadIdx.x;

    __shared__ double sh_shortest[TT];
    __shared__ double sh_v[TT];
    __shared__ int sh_path[TT];
    __shared__ int sh_row4col[TT];
    __shared__ unsigned char sh_SC[TT];
    __shared__ double sh_u[OO];
    __shared__ int sh_col4row[OO];
    __shared__ unsigned char sh_SR[OO];
    __shared__ double red_val[NT];
    __shared__ int red_idx[NT];
    __shared__ int sh_i, sh_sink;
    __shared__ double sh_minval;

    for (int j = tid; j < TT; j += NT) { sh_v[j] = 0.0; sh_row4col[j] = -1; }
    if (tid < OO) { sh_u[tid] = 0.0; sh_col4row[tid] = -1; }
    __syncthreads();

    const float* cb = cost + (size_t)b * OO * TT;

    for (int cur = 0; cur < OO; ++cur) {
        for (int j = tid; j < TT; j += NT) {
            sh_shortest[j] = INFINITY;
            sh_path[j] = -1;
            sh_SC[j] = 0;
        }
        if (tid < OO) sh_SR[tid] = 0;
        if (tid == 0) { sh_i = cur; sh_minval = 0.0; sh_sink = -1; }
        __syncthreads();

        while (true) {
            int i = sh_i;
            double minval = sh_minval;
            if (tid == 0) sh_SR[i] = 1;
            double ui = sh_u[i];
            const float* crow = cb + (size_t)i * TT;
            for (int j = tid; j < TT; j += NT) {
                if (!sh_SC[j]) {
                    // numpy: r = min_val + c[i] - u[i] - v   (left-to-right)
                    double r = ((minval + (double)crow[j]) - ui) - sh_v[j];
                    if (r < sh_shortest[j]) { sh_shortest[j] = r; sh_path[j] = i; }
                }
            }
            __syncthreads();

            // masked argmin, first-index tie-break
            double bv = INFINITY;
            int bj = TT;
            for (int j = tid; j < TT; j += NT) {
                if (!sh_SC[j]) {
                    double s = sh_shortest[j];
                    if (s < bv) { bv = s; bj = j; }
                }
            }
            red_val[tid] = bv;
            red_idx[tid] = bj;
            __syncthreads();
            for (int s = NT / 2; s > 0; s >>= 1) {
                if (tid < s) {
                    double ov = red_val[tid + s];
                    int oj = red_idx[tid + s];
                    if (ov < red_val[tid] ||
                        (ov == red_val[tid] && oj < red_idx[tid])) {
                        red_val[tid] = ov;
                        red_idx[tid] = oj;
                    }
                }
                __syncthreads();
            }
            if (tid == 0) {
                int j = red_idx[0];
                sh_minval = red_val[0];
                sh_SC[j] = 1;
                if (sh_row4col[j] < 0) sh_sink = j;
                else sh_i = sh_row4col[j];
            }
            __syncthreads();
            if (sh_sink >= 0) break;
        }

        double minval = sh_minval;
        int sink = sh_sink;
        // dual updates (same per-element expression order as numpy)
        if (tid < OO) {
            if (tid == cur) sh_u[tid] = sh_u[tid] + minval;
            else if (sh_SR[tid])
                sh_u[tid] = sh_u[tid] + (minval - sh_shortest[sh_col4row[tid]]);
        }
        for (int j = tid; j < TT; j += NT) {
            if (sh_SC[j]) sh_v[j] = sh_v[j] - (minval - sh_shortest[j]);
        }
        __syncthreads();
        // augment (sequential, thread 0)
        if (tid == 0) {
            int j = sink;
            while (true) {
                int ii = sh_path[j];
                sh_row4col[j] = ii;
                int tmp = sh_col4row[ii];
                sh_col4row[ii] = j;
                j = tmp;
                if (ii == cur) break;
            }
        }
        __syncthreads();
    }

    // order = argsort(col4row); pred_idx = col4row[order]; tgt_idx = order
    // col4row values are distinct tokens -> rank by counting.
    if (tid < OO) {
        int my = sh_col4row[tid];
        int rank = 0;
        for (int o = 0; o < OO; ++o) rank += (sh_col4row[o] < my) ? 1 : 0;
        out[(size_t)b * OO + rank] = my;                   // pred_idx
        out[(size_t)(BB + b) * OO + rank] = tid;           // tgt_idx
    }
}

// ---------------------------------------------------------------------------
extern "C" void kernel_launch(void* const* d_in, const int* in_sizes, int n_in,
                              void* d_out, int out_size, void* d_ws, size_t ws_size,
                              hipStream_t stream) {
    const float* pred_bboxes = (const float*)d_in[0];    // [B,T,4]
    const float* target_bboxes = (const float*)d_in[1];  // [B,O,4]
    const float* pred_classes = (const float*)d_in[2];   // [B,T,C]
    const int* target_classes = (const int*)d_in[3];     // [B,O]
    int* out = (int*)d_out;                              // [2,B,O] int32

    // workspace: cost [B][O][T] fp32 (32 MB) + xmax/lse [B*T] (512 KB)
    float* cost = (float*)d_ws;
    float* xmax = cost + (size_t)BB * OO * TT;
    float* lse = xmax + (size_t)BB * TT;

    lse_kernel<<<(BB * TT) / NT, NT, 0, stream>>>(pred_classes, xmax, lse);
    cost_kernel<<<BB * OO, NT, 0, stream>>>(pred_bboxes, target_bboxes,
                                            pred_classes, target_classes,
                                            xmax, lse, cost);
    lsa_kernel<<<BB, NT, 0, stream>>>(cost, out);
}

// Round 2
// 494.697 us; speedup vs baseline: 2.0651x; 2.0651x over previous
//
#include <hip/hip_runtime.h>
#include <math.h>
#include <float.h>

// Problem dims (fixed by setup_inputs)
#define BB 32
#define TT 2048
#define OO 128
#define CC 80
#define EPSF 1e-7f
#define NT 256
#define NW (NT / 64)

// ---------------------------------------------------------------------------
// Fused cost kernel: block = (t-tile of 256, b). Computes log-softmax
// normalizers per token (same sequential op order as before -> identical fp32
// bits) then loops over the 128 targets writing coalesced cost rows.
// cost layout: [B][O][T] (LSA row layout).
// ---------------------------------------------------------------------------
__global__ __launch_bounds__(NT) void cost_fused_kernel(
    const float* __restrict__ pb, const float* __restrict__ tb,
    const float* __restrict__ cls, const int* __restrict__ tcls,
    float* __restrict__ cost) {
#pragma clang fp contract(off)
    int b = blockIdx.y;
    int t0 = blockIdx.x * NT;
    int tid = threadIdx.x;
    int t = t0 + tid;

    // per-target params in LDS
    __shared__ float s_x1[OO], s_y1[OO], s_x2[OO], s_y2[OO], s_w2h2[OO];
    __shared__ int s_tc[OO];
    if (tid < OO) {
        float4 tbox = ((const float4*)tb)[b * OO + tid];
        float x1 = tbox.x - tbox.z / 2.f;
        float y1 = tbox.y - tbox.w / 2.f;
        float x2 = tbox.x + tbox.z / 2.f;
        float y2 = tbox.y + tbox.w / 2.f;
        s_x1[tid] = x1; s_y1[tid] = y1; s_x2[tid] = x2; s_y2[tid] = y2;
        float w2 = x2 - x1;
        float h2 = (y2 - y1) + EPSF;
        s_w2h2[tid] = w2 * h2;
        s_tc[tid] = tcls[b * OO + tid];
    }
    __syncthreads();

    size_t bt = (size_t)b * TT + t;
    // pred box
    float4 pbox = ((const float4*)pb)[bt];
    float b1x1 = pbox.x - pbox.z / 2.f;
    float b1y1 = pbox.y - pbox.w / 2.f;
    float b1x2 = pbox.x + pbox.z / 2.f;
    float b1y2 = pbox.y + pbox.w / 2.f;
    float w1 = b1x2 - b1x1;
    float h1 = (b1y2 - b1y1) + EPSF;
    float w1h1 = w1 * h1;

    // log-softmax normalizers, strictly sequential in c (bit-identical to ref)
    const float* x = cls + bt * CC;
    float xv[CC];
    #pragma unroll
    for (int c4 = 0; c4 < CC / 4; ++c4) {
        float4 v = ((const float4*)x)[c4];
        xv[c4 * 4 + 0] = v.x; xv[c4 * 4 + 1] = v.y;
        xv[c4 * 4 + 2] = v.z; xv[c4 * 4 + 3] = v.w;
    }
    float m = xv[0];
    #pragma unroll
    for (int c = 1; c < CC; ++c) m = fmaxf(m, xv[c]);
    float s = 0.f;
    #pragma unroll
    for (int c = 0; c < CC; ++c) s += expf(xv[c] - m);
    float ls = logf(s);

    float* cbt = cost + (size_t)b * OO * TT + t0;
    for (int o = 0; o < OO; ++o) {
        float b2x1 = s_x1[o], b2y1 = s_y1[o], b2x2 = s_x2[o], b2y2 = s_y2[o];
        float iw = fminf(b1x2, b2x2) - fmaxf(b1x1, b2x1);
        float ih = fminf(b1y2, b2y2) - fmaxf(b1y1, b2y1);
        iw = fmaxf(iw, 0.f);
        ih = fmaxf(ih, 0.f);
        float inter = iw * ih;
        float uni = ((w1h1 + s_w2h2[o]) - inter) + EPSF;
        float iou = inter / uni;
        float cw = fmaxf(b1x2, b2x2) - fminf(b1x1, b2x1);
        float ch = fmaxf(b1y2, b2y2) - fminf(b1y1, b2y1);
        float c_area = (cw * ch) + EPSF;
        float giou = iou - (c_area - uni) / c_area;
        float bbox_loss = 1.0f - giou;

        float xc = xv[s_tc[o]];
        float shifted = xc - m;
        float cls_neg = -(shifted - ls);

        cbt[(size_t)o * TT + tid] = bbox_loss + cls_neg;
    }
}

// ---------------------------------------------------------------------------
// Jonker-Volgenant LSA, one block per batch. Fused update+argmin sweep with
// NaN-masking of selected columns; wave shuffle reductions; 2 barriers per
// shortest-path step. All fp64 expression orders identical to numpy ref.
// ---------------------------------------------------------------------------
__global__ __launch_bounds__(NT) void lsa_kernel(const float* __restrict__ cost,
                                                 int* __restrict__ out) {
    int b = blockIdx.x;
    int tid = threadIdx.x;
    int lane = tid & 63;
    int wave = tid >> 6;

    __shared__ double sh_key[TT];   // shortest[], NaN = column selected (SC)
    __shared__ double sh_v[TT];
    __shared__ int sh_path[TT];
    __shared__ int sh_row4col[TT];
    __shared__ double sh_u[OO];
    __shared__ int sh_col4row[OO];
    __shared__ int sh_selj[OO + 8];     // selected column per step
    __shared__ double sh_selm[OO + 8];  // its shortest value (minval at pick)
    __shared__ int sh_selrow[OO + 8];   // row entered from that column
    __shared__ double red_val[NW];
    __shared__ int red_idx[NW];
    __shared__ int sh_i, sh_sink, sh_L;
    __shared__ double sh_minval;

    const double DNAN = __builtin_nan("");

    for (int j = tid; j < TT; j += NT) { sh_v[j] = 0.0; sh_row4col[j] = -1; }
    if (tid < OO) { sh_u[tid] = 0.0; sh_col4row[tid] = -1; }
    __syncthreads();

    const float* cb = cost + (size_t)b * OO * TT;

    for (int cur = 0; cur < OO; ++cur) {
        #pragma unroll
        for (int k = 0; k < TT / NT; ++k) sh_key[tid + k * NT] = INFINITY;
        if (tid == 0) { sh_i = cur; sh_minval = 0.0; sh_sink = -1; sh_L = 0; }
        __syncthreads();

        while (true) {
            int i = sh_i;
            double mv = sh_minval;
            double ui = sh_u[i];
            const float* crow = cb + (size_t)i * TT;

            float cv[TT / NT];
            #pragma unroll
            for (int k = 0; k < TT / NT; ++k) cv[k] = crow[tid + k * NT];

            double bv = INFINITY;
            int bj = TT;
            #pragma unroll
            for (int k = 0; k < TT / NT; ++k) {
                int j = tid + k * NT;
                // numpy order: r = min_val + c[i] - u[i] - v
                double r = ((mv + (double)cv[k]) - ui) - sh_v[j];
                double kk = sh_key[j];        // NaN if selected -> all cmps false
                if (r < kk) { sh_key[j] = r; sh_path[j] = i; kk = r; }
                if (kk < bv) { bv = kk; bj = j; }
            }
            // wave-level (val, idx) min, first-index tie-break
            #pragma unroll
            for (int off = 32; off > 0; off >>= 1) {
                double ov = __shfl_down(bv, off);
                int oj = __shfl_down(bj, off);
                if (ov < bv || (ov == bv && oj < bj)) { bv = ov; bj = oj; }
            }
            if (lane == 0) { red_val[wave] = bv; red_idx[wave] = bj; }
            __syncthreads();

            if (tid == 0) {
                bv = red_val[0]; bj = red_idx[0];
                #pragma unroll
                for (int w = 1; w < NW; ++w) {
                    double ov = red_val[w]; int oj = red_idx[w];
                    if (ov < bv || (ov == bv && oj < bj)) { bv = ov; bj = oj; }
                }
                sh_minval = bv;
                sh_key[bj] = DNAN;            // mark SC
                int L = sh_L;
                sh_selj[L] = bj;
                sh_selm[L] = bv;
                int r4 = sh_row4col[bj];
                if (r4 < 0) sh_sink = bj;
                else { sh_i = r4; sh_selrow[L] = r4; }
                sh_L = L + 1;
            }
            __syncthreads();
            if (sh_sink >= 0) break;
        }

        double M = sh_minval;
        int L = sh_L;
        // duals: u[cur]+=M; u[visited rows]+=M-m_k; v[selected cols]-=M-m_k
        if (tid < L) sh_v[sh_selj[tid]] = sh_v[sh_selj[tid]] - (M - sh_selm[tid]);
        if (tid < L - 1)
            sh_u[sh_selrow[tid]] = sh_u[sh_selrow[tid]] + (M - sh_selm[tid]);
        if (tid == 0) {
            sh_u[cur] = sh_u[cur] + M;
            // augment
            int j = sh_sink;
            while (true) {
                int ii = sh_path[j];
                sh_row4col[j] = ii;
                int tmp = sh_col4row[ii];
                sh_col4row[ii] = j;
                j = tmp;
                if (ii == cur) break;
            }
        }
        __syncthreads();
    }

    // order = argsort(col4row); pred_idx = col4row[order]; tgt_idx = order
    if (tid < OO) {
        int my = sh_col4row[tid];
        int rank = 0;
        for (int o = 0; o < OO; ++o) rank += (sh_col4row[o] < my) ? 1 : 0;
        out[(size_t)b * OO + rank] = my;         // pred_idx
        out[(size_t)(BB + b) * OO + rank] = tid; // tgt_idx
    }
}

// ---------------------------------------------------------------------------
extern "C" void kernel_launch(void* const* d_in, const int* in_sizes, int n_in,
                              void* d_out, int out_size, void* d_ws, size_t ws_size,
                              hipStream_t stream) {
    const float* pred_bboxes = (const float*)d_in[0];    // [B,T,4]
    const float* target_bboxes = (const float*)d_in[1];  // [B,O,4]
    const float* pred_classes = (const float*)d_in[2];   // [B,T,C]
    const int* target_classes = (const int*)d_in[3];     // [B,O]
    int* out = (int*)d_out;                              // [2,B,O] int32

    float* cost = (float*)d_ws;  // [B][O][T] fp32 (32 MB)

    dim3 cgrid(TT / NT, BB);
    cost_fused_kernel<<<cgrid, NT, 0, stream>>>(pred_bboxes, target_bboxes,
                                                pred_classes, target_classes,
                                                cost);
    lsa_kernel<<<BB, NT, 0, stream>>>(cost, out);
}

// Round 3
// 467.462 us; speedup vs baseline: 2.1854x; 1.0583x over previous
//
#include <hip/hip_runtime.h>
#include <math.h>
#include <float.h>

// Problem dims (fixed by setup_inputs)
#define BB 32
#define TT 2048
#define OO 128
#define CC 80
#define EPSF 1e-7f
#define NT 256
#define SLOTS (TT / NT)   // 8 columns per thread
#define CPAD 84           // padded LDS class-row stride (floats, mult of 4)

// ---------------------------------------------------------------------------
// Fused cost kernel: block = (t-tile of 256, b). Class tile staged in LDS
// (no dynamic-indexed register array -> no scratch spill). Log-softmax in the
// exact sequential op order of the reference -> bit-identical fp32 cost.
// cost layout: [B][O][T].
// ---------------------------------------------------------------------------
__global__ __launch_bounds__(NT) void cost_fused_kernel(
    const float* __restrict__ pb, const float* __restrict__ tb,
    const float* __restrict__ cls, const int* __restrict__ tcls,
    float* __restrict__ cost) {
#pragma clang fp contract(off)
    int b = blockIdx.y;
    int t0 = blockIdx.x * NT;
    int tid = threadIdx.x;

    __shared__ float s_xv[NT * CPAD];   // 256 tokens x 80 classes (pad 84)
    __shared__ float s_x1[OO], s_y1[OO], s_x2[OO], s_y2[OO], s_w2h2[OO];
    __shared__ int s_tc[OO];

    // stage class tile: coalesced float4 global reads, aligned LDS writes
    // (80 % 4 == 0 so a float4 never straddles a token row)
    const float* cbase = cls + ((size_t)b * TT + t0) * CC;
    #pragma unroll
    for (int k = 0; k < (NT * CC) / (NT * 4); ++k) {   // 20 iters
        int idx4 = (k * NT + tid) * 4;
        float4 vv = *(const float4*)(cbase + idx4);
        int r = idx4 / CC;
        int c = idx4 - r * CC;
        *(float4*)(&s_xv[r * CPAD + c]) = vv;
    }
    if (tid < OO) {
        float4 tbox = ((const float4*)tb)[b * OO + tid];
        float x1 = tbox.x - tbox.z / 2.f;
        float y1 = tbox.y - tbox.w / 2.f;
        float x2 = tbox.x + tbox.z / 2.f;
        float y2 = tbox.y + tbox.w / 2.f;
        s_x1[tid] = x1; s_y1[tid] = y1; s_x2[tid] = x2; s_y2[tid] = y2;
        float w2 = x2 - x1;
        float h2 = (y2 - y1) + EPSF;
        s_w2h2[tid] = w2 * h2;
        s_tc[tid] = tcls[b * OO + tid];
    }
    __syncthreads();

    size_t bt = (size_t)b * TT + t0 + tid;
    float4 pbox = ((const float4*)pb)[bt];
    float b1x1 = pbox.x - pbox.z / 2.f;
    float b1y1 = pbox.y - pbox.w / 2.f;
    float b1x2 = pbox.x + pbox.z / 2.f;
    float b1y2 = pbox.y + pbox.w / 2.f;
    float w1 = b1x2 - b1x1;
    float h1 = (b1y2 - b1y1) + EPSF;
    float w1h1 = w1 * h1;

    // log-softmax normalizers, strictly sequential in c (bit-identical)
    const float* xr = &s_xv[tid * CPAD];
    float m = xr[0];
    #pragma unroll
    for (int c = 1; c < CC; ++c) m = fmaxf(m, xr[c]);
    float ssum = 0.f;
    #pragma unroll
    for (int c = 0; c < CC; ++c) ssum += expf(xr[c] - m);
    float ls = logf(ssum);

    float* cbt = cost + (size_t)b * OO * TT + t0;
    for (int o = 0; o < OO; ++o) {
        float b2x1 = s_x1[o], b2y1 = s_y1[o], b2x2 = s_x2[o], b2y2 = s_y2[o];
        float iw = fminf(b1x2, b2x2) - fmaxf(b1x1, b2x1);
        float ih = fminf(b1y2, b2y2) - fmaxf(b1y1, b2y1);
        iw = fmaxf(iw, 0.f);
        ih = fmaxf(ih, 0.f);
        float inter = iw * ih;
        float uni = ((w1h1 + s_w2h2[o]) - inter) + EPSF;
        float iou = inter / uni;
        float cw = fmaxf(b1x2, b2x2) - fminf(b1x1, b2x1);
        float ch = fmaxf(b1y2, b2y2) - fminf(b1y1, b2y1);
        float c_area = (cw * ch) + EPSF;
        float giou = iou - (c_area - uni) / c_area;
        float bbox_loss = 1.0f - giou;

        float xc = xr[s_tc[o]];
        float shifted = xc - m;
        float cls_neg = -(shifted - ls);

        cbt[(size_t)o * TT + tid] = bbox_loss + cls_neg;
    }
}

// ---------------------------------------------------------------------------
// Jonker-Volgenant LSA, one block per batch. v[] and shortest[] (key) are
// register-resident (8 cols/thread, j = tid*8+s); SC is a per-lane bitmask.
// One __syncthreads per shortest-path step: wave butterfly -> post per-wave
// candidate (double-buffered by parity) -> barrier -> every thread combines
// the 4 candidates redundantly in registers. All fp64 expression orders
// identical to the numpy reference (bit-exact assignment).
// ---------------------------------------------------------------------------
__global__ __launch_bounds__(NT) void lsa_kernel(const float* __restrict__ cost,
                                                 int* __restrict__ out) {
#pragma clang fp contract(off)
    int b = blockIdx.x;
    int tid = threadIdx.x;
    int lane = tid & 63;
    int wave = tid >> 6;

    __shared__ int sh_path[TT];        // predecessor row per col
    __shared__ int sh_row4col[TT];
    __shared__ double sh_u[OO];
    __shared__ int sh_col4row[OO];
    __shared__ double sh_selm[OO + 8]; // shortest value at each selection
    __shared__ int sh_selrow[OO + 8];  // row entered from each selected col
    __shared__ double cand_val[2][4];
    __shared__ int cand_idx[2][4];

    double v_[SLOTS];
    double key[SLOTS];
    #pragma unroll
    for (int s = 0; s < SLOTS; ++s) v_[s] = 0.0;

    for (int j = tid; j < TT; j += NT) sh_row4col[j] = -1;
    if (tid < OO) { sh_u[tid] = 0.0; sh_col4row[tid] = -1; }
    __syncthreads();

    const float* cb = cost + (size_t)b * OO * TT;
    const int jbase = tid * SLOTS;

    for (int cur = 0; cur < OO; ++cur) {
        #pragma unroll
        for (int s = 0; s < SLOTS; ++s) key[s] = INFINITY;
        int selbits = 0;
        double mv = 0.0;
        int i = cur;
        double ui = sh_u[cur];
        int L = 0, parity = 0, sink = -1;

        while (true) {
            const float* crow = cb + (size_t)i * TT + jbase;
            float4 c0 = *(const float4*)crow;
            float4 c1 = *(const float4*)(crow + 4);
            float cv[SLOTS] = {c0.x, c0.y, c0.z, c0.w, c1.x, c1.y, c1.z, c1.w};

            double bv = INFINITY;
            int bj = TT;
            #pragma unroll
            for (int s = 0; s < SLOTS; ++s) {
                if (!((selbits >> s) & 1)) {
                    // numpy order: r = min_val + c[i] - u[i] - v
                    double r = ((mv + (double)cv[s]) - ui) - v_[s];
                    if (r < key[s]) { key[s] = r; sh_path[jbase + s] = i; }
                    double kk = key[s];
                    if (kk < bv) { bv = kk; bj = jbase + s; }  // s asc = j asc
                }
            }
            // wave butterfly lexmin (val, idx) — all lanes end with wave min
            #pragma unroll
            for (int off = 1; off < 64; off <<= 1) {
                double ov = __shfl_xor(bv, off);
                int oj = __shfl_xor(bj, off);
                if (ov < bv || (ov == bv && oj < bj)) { bv = ov; bj = oj; }
            }
            if (lane == 0) { cand_val[parity][wave] = bv; cand_idx[parity][wave] = bj; }
            __syncthreads();

            // every thread combines the 4 wave candidates (broadcast reads)
            double MV = cand_val[parity][0];
            int BJ = cand_idx[parity][0];
            #pragma unroll
            for (int w = 1; w < 4; ++w) {
                double ov = cand_val[parity][w];
                int oj = cand_idx[parity][w];
                if (ov < MV || (ov == MV && oj < BJ)) { MV = ov; BJ = oj; }
            }
            mv = MV;
            if ((BJ >> 3) == tid) selbits |= 1 << (BJ & 7);  // mark SC (owner)

            int r4 = sh_row4col[BJ];   // broadcast LDS read
            if (r4 < 0) { sink = BJ; break; }
            if (tid == 0) { sh_selm[L] = MV; sh_selrow[L] = r4; }
            i = r4;
            ui = sh_u[i];
            L++;
            parity ^= 1;
        }

        double M = mv;
        // v[SC] -= M - shortest[SC]  (register-resident, per owner lane)
        #pragma unroll
        for (int s = 0; s < SLOTS; ++s)
            if ((selbits >> s) & 1) v_[s] = v_[s] - (M - key[s]);
        // u[visited rows] += M - shortest[their col]  (distinct rows)
        for (int k = tid; k < L; k += NT)
            sh_u[sh_selrow[k]] = sh_u[sh_selrow[k]] + (M - sh_selm[k]);
        if (tid == 0) {
            sh_u[cur] = sh_u[cur] + M;
            // augment along predecessor path (SC cols only -> path[] frozen)
            int j = sink;
            while (true) {
                int ii = sh_path[j];
                sh_row4col[j] = ii;
                int tmp = sh_col4row[ii];
                sh_col4row[ii] = j;
                j = tmp;
                if (ii == cur) break;
            }
        }
        __syncthreads();   // orders augment/u-writes vs next path
    }

    // order = argsort(col4row); pred_idx = col4row[order]; tgt_idx = order
    if (tid < OO) {
        int my = sh_col4row[tid];
        int rank = 0;
        for (int o = 0; o < OO; ++o) rank += (sh_col4row[o] < my) ? 1 : 0;
        out[(size_t)b * OO + rank] = my;         // pred_idx
        out[(size_t)(BB + b) * OO + rank] = tid; // tgt_idx
    }
}

// ---------------------------------------------------------------------------
extern "C" void kernel_launch(void* const* d_in, const int* in_sizes, int n_in,
                              void* d_out, int out_size, void* d_ws, size_t ws_size,
                              hipStream_t stream) {
    const float* pred_bboxes = (const float*)d_in[0];    // [B,T,4]
    const float* target_bboxes = (const float*)d_in[1];  // [B,O,4]
    const float* pred_classes = (const float*)d_in[2];   // [B,T,C]
    const int* target_classes = (const int*)d_in[3];     // [B,O]
    int* out = (int*)d_out;                              // [2,B,O] int32

    float* cost = (float*)d_ws;  // [B][O][T] fp32 (32 MB)

    dim3 cgrid(TT / NT, BB);
    cost_fused_kernel<<<cgrid, NT, 0, stream>>>(pred_bboxes, target_bboxes,
                                                pred_classes, target_classes,
                                                cost);
    lsa_kernel<<<BB, NT, 0, stream>>>(cost, out);
}